// Round 6
// baseline (1078.566 us; speedup 1.0000x reference)
//
#include <hip/hip_runtime.h>
#include <stdint.h>

#define N_ATOMS 100000
#define NS 4
#define NE 8
#define D0 384
#define D1 160
#define D2 128
#define D3 96
#define BUCKET_CAP 32768

// ---- workspace layout (bytes) ----
#define IDX_OFF_B 256
#define IDX_CAP (NS*BUCKET_CAP)               // 131072 ints
#define W1B_OFF (IDX_OFF_B + IDX_CAP*4)
#define W1_TOT (NS*NE*D0*D1)
#define W2_TOT (NS*NE*D1*D2)
#define W3_TOT (NS*NE*D2*D3)
#define W2B_OFF (W1B_OFF + W1_TOT*2)
#define W3B_OFF (W2B_OFF + W2_TOT*2)

// blocks: 4 waves * 32 atoms = 128 atoms per block (wave-private tiles).
// nb = sum_s ceil(count_s/128) in [782,785]. Phase 1 = 768 8-e blocks
// (XCD-chunked); remaining <=17 blocks run as (block, e-pair) tail units.
#define P1BLOCKS 768
#define GRID_MLP (P1BLOCKS + 17*4)            // 836

// merged prep kernel: scatter blocks then convert blocks
#define SCB ((N_ATOMS + 255)/256)             // 391
#define CONV_TOT (W1_TOT + W2_TOT + W3_TOT)
#define CVB ((CONV_TOT + 255)/256)            // 9344

typedef __attribute__((ext_vector_type(8))) _Float16 h8v;
typedef __attribute__((ext_vector_type(4))) float f4v;

__device__ __forceinline__ unsigned short f2h(float x){
    _Float16 h = (_Float16)x;
    return *(unsigned short*)&h;
}

// jax.nn.celu(x, 0.1) = x>0 ? x : 0.1*expm1(x/0.1)
__device__ __forceinline__ float celu01(float v){
    return v > 0.f ? v : 0.1f * (__expf(fminf(v, 0.f) * 10.f) - 1.f);
}

// byte offset into a swizzled X tile: XOR row-bits into the 16B-slot bits.
// Validated end-to-end in R4/R5 (absmax 0.0); keeps 16B alignment.
__device__ __forceinline__ int swzb(int row, int colByte, int strideB){
    return (row * strideB + colByte) ^ ((row & 7) << 4);
}

__global__ void k_init(int* hdr, float* out){
    int i = threadIdx.x;
    if (i < 32) hdr[i] = 0;
    if (i == 0) out[0] = 0.f;
}

// merged prep: blocks [0,SCB) scatter species -> buckets; blocks [SCB,SCB+CVB)
// convert W1..W3 fp32 -> fp16 fragment order, INPUT-ORDERED (coalesced reads,
// scatter u16 writes -- stores don't stall; the old gather-read was 640B-strided).
__global__ __launch_bounds__(256) void k_prep(const int* __restrict__ species,
                                              int* __restrict__ hdr,
                                              int* __restrict__ idx,
                                              const float* __restrict__ W1,
                                              const float* __restrict__ W2,
                                              const float* __restrict__ W3,
                                              unsigned short* __restrict__ W1b,
                                              unsigned short* __restrict__ W2b,
                                              unsigned short* __restrict__ W3b){
    int tid = threadIdx.x;
    if (blockIdx.x < SCB){
        __shared__ int lc[NS];
        __shared__ int lb[NS];
        if (tid < NS) lc[tid] = 0;
        __syncthreads();
        int i = blockIdx.x * 256 + tid;
        int s = 0, r = 0;
        bool valid = (i < N_ATOMS);
        if (valid){
            s = species[i];
            r = atomicAdd(&lc[s], 1);
        }
        __syncthreads();
        if (tid < NS) lb[tid] = atomicAdd(&hdr[tid], lc[tid]);
        __syncthreads();
        if (valid) idx[s * BUCKET_CAP + lb[s] + r] = i;
        return;
    }
    int i = (blockIdx.x - SCB) * 256 + tid;
    // fragment offset: [net][nt][kt][lane][j], lane = ((k>>3)&3)<<4 | (n&15), j = k&7
    if (i < W1_TOT){
        int net = i / (D0*D1), r = i % (D0*D1);
        int k = r / D1, n = r % D1;
        int off = net*(D0*D1) + (n>>4)*(D0*16) + (k>>5)*512
                + (((((k>>3)&3)<<4) | (n&15))<<3) + (k&7);
        W1b[off] = f2h(W1[i]);
    } else if (i < W1_TOT + W2_TOT){
        int i2 = i - W1_TOT;
        int net = i2 / (D1*D2), r = i2 % (D1*D2);
        int k = r / D2, n = r % D2;
        int off = net*(D1*D2) + (n>>4)*(D1*16) + (k>>5)*512
                + (((((k>>3)&3)<<4) | (n&15))<<3) + (k&7);
        W2b[off] = f2h(W2[i2]);
    } else if (i < W1_TOT + W2_TOT + W3_TOT){
        int i3 = i - W1_TOT - W2_TOT;
        int net = i3 / (D2*D3), r = i3 % (D2*D3);
        int k = r / D3, n = r % D3;
        int off = net*(D2*D3) + (n>>4)*(D2*16) + (k>>5)*512
                + (((((k>>3)&3)<<4) | (n&15))<<3) + (k&7);
        W3b[off] = f2h(W3[i3]);
    }
}

// Barrier-free MLP (R2 body, proven 358us): one WAVE = one 32-atom tile, B
// fragments stream global->reg with next-nt double-buffer. X1/X2 union one
// swizzled 10240 B per-wave LDS region -> block LDS 40960 B = 4 blocks/CU.
// NOTE: __launch_bounds__(256, 2) is load-bearing: min-waves>=3 makes the
// allocator pick 84 VGPRs -> 164 MB scratch spill (measured R1/R4).
__global__ __launch_bounds__(256, 2) void k_mlp(
    const float* __restrict__ aev, const int* __restrict__ hdr, const int* __restrict__ idx,
    const unsigned short* __restrict__ W1b, const unsigned short* __restrict__ W2b,
    const unsigned short* __restrict__ W3b,
    const float* __restrict__ b1, const float* __restrict__ b2, const float* __restrict__ b3,
    const float* __restrict__ W4, const float* __restrict__ b4, float* __restrict__ out)
{
    __shared__ __align__(128) unsigned short sX[4][5120];   // 40960 B total

    int tid = threadIdx.x;
    int lane = tid & 63, wid = tid >> 6;

    // ---- block -> (species, atom range, e range) ----
    int c0 = hdr[0], c1 = hdr[1], c2 = hdr[2], c3 = hdr[3];
    int n0 = (c0 + 127) >> 7, n1 = (c1 + 127) >> 7, n2 = (c2 + 127) >> 7, n3 = (c3 + 127) >> 7;
    int p1 = n0, p2 = p1 + n1, p3 = p2 + n2, nb = p3 + n3;   // nb in [782,785]

    int g, eBeg, eEnd;
    if (blockIdx.x < P1BLOCKS){
        g = (blockIdx.x & 7) * 96 + (blockIdx.x >> 3);        // XCD-chunked
        eBeg = 0; eEnd = NE;
    } else {
        int RT = nb - P1BLOCKS;                               // <= 17
        int u = blockIdx.x - P1BLOCKS;
        if (u >= RT * 4) return;                              // block-uniform exit
        g = P1BLOCKS + (u >> 2);
        eBeg = (u & 3) * 2; eEnd = eBeg + 2;
    }

    int s   = (g >= p3) ? 3 : (g >= p2) ? 2 : (g >= p1) ? 1 : 0;
    int blk = g - (s == 0 ? 0 : s == 1 ? p1 : s == 2 ? p2 : p3);
    int cs  = (s == 0 ? c0 : s == 1 ? c1 : s == 2 ? c2 : c3);
    int base = blk * 128 + wid * 32;
    int nValid = cs - base; if (nValid > 32) nValid = 32; if (nValid < 0) nValid = 0;
    const int* myIdx = idx + s * BUCKET_CAP + base;

    int m = lane & 15, quad = lane >> 4;
    char* xb = (char*)sX[wid];

    // ---- layer-1 A fragments from global AEV (fp32->fp16), e-invariant, NT loads ----
    h8v A1[2][12];
    #pragma unroll
    for (int mt = 0; mt < 2; mt++){
        int slot = mt*16 + m;
        int atom = 0;
        if (nValid > 0) atom = myIdx[slot < nValid ? slot : nValid - 1];
        const float* ap = aev + (size_t)atom * D0 + quad*8;
        #pragma unroll
        for (int kt = 0; kt < 12; kt++){
            f4v u = __builtin_nontemporal_load((const f4v*)(ap + kt*32));
            f4v v = __builtin_nontemporal_load((const f4v*)(ap + kt*32 + 4));
            h8v f;
            f[0] = (_Float16)u.x; f[1] = (_Float16)u.y; f[2] = (_Float16)u.z; f[3] = (_Float16)u.w;
            f[4] = (_Float16)v.x; f[5] = (_Float16)v.y; f[6] = (_Float16)v.z; f[7] = (_Float16)v.w;
            A1[mt][kt] = f;
        }
    }

    float e0[4] = {0.f,0.f,0.f,0.f};
    float e1[4] = {0.f,0.f,0.f,0.f};

    #pragma unroll 1
    for (int e = eBeg; e < eEnd; e++){
        int net = s * NE + e;

        // ---------- layer 1: A1(regs) [K=384] -> X1 [N=160] ----------
        // full next-nt B prefetch (12 frags in flight) + even/odd acc chains
        {
            const unsigned short* wf = W1b + (size_t)net * (D0*D1) + lane*8;
            h8v Bb[2][12];
            #pragma unroll
            for (int kt = 0; kt < 12; kt++) Bb[0][kt] = *(const h8v*)(wf + kt*512);
            #pragma unroll
            for (int nt = 0; nt < 10; nt++){
                int cur = nt & 1, nxt = cur ^ 1;
                if (nt < 9){
                    const unsigned short* bp = wf + (nt+1)*6144;
                    #pragma unroll
                    for (int kt = 0; kt < 12; kt++) Bb[nxt][kt] = *(const h8v*)(bp + kt*512);
                }
                float bi1 = b1[net*D1 + nt*16 + m];
                f4v a0e = {bi1, bi1, bi1, bi1}, a1e = a0e;
                f4v a0o = {0.f,0.f,0.f,0.f},   a1o = a0o;
                #pragma unroll
                for (int kt = 0; kt < 12; kt += 2){
                    a0e = __builtin_amdgcn_mfma_f32_16x16x32_f16(A1[0][kt],   Bb[cur][kt],   a0e, 0, 0, 0);
                    a1e = __builtin_amdgcn_mfma_f32_16x16x32_f16(A1[1][kt],   Bb[cur][kt],   a1e, 0, 0, 0);
                    a0o = __builtin_amdgcn_mfma_f32_16x16x32_f16(A1[0][kt+1], Bb[cur][kt+1], a0o, 0, 0, 0);
                    a1o = __builtin_amdgcn_mfma_f32_16x16x32_f16(A1[1][kt+1], Bb[cur][kt+1], a1o, 0, 0, 0);
                }
                f4v a0 = a0e + a0o, a1 = a1e + a1o;
                int colB = (nt*16 + m)*2;
                #pragma unroll
                for (int r = 0; r < 4; r++){
                    *(unsigned short*)(xb + swzb(quad*4 + r,      colB, 320)) = f2h(celu01(a0[r]));
                    *(unsigned short*)(xb + swzb(16 + quad*4 + r, colB, 320)) = f2h(celu01(a1[r]));
                }
            }
        }

        // ---------- layer 2: X1 [K=160] -> X2 [N=128] ----------
        {
            h8v A2[2][5];
            #pragma unroll
            for (int mt = 0; mt < 2; mt++)
                #pragma unroll
                for (int kt = 0; kt < 5; kt++)
                    A2[mt][kt] = *(const h8v*)(xb + swzb(mt*16 + m, (kt*32 + quad*8)*2, 320));
            const unsigned short* wf = W2b + (size_t)net * (D1*D2) + lane*8;
            h8v Bb[2][5];
            #pragma unroll
            for (int kt = 0; kt < 5; kt++) Bb[0][kt] = *(const h8v*)(wf + kt*512);
            #pragma unroll
            for (int nt = 0; nt < 8; nt++){
                int cur = nt & 1, nxt = cur ^ 1;
                if (nt < 7){
                    const unsigned short* bp = wf + (nt+1)*2560;
                    #pragma unroll
                    for (int kt = 0; kt < 5; kt++) Bb[nxt][kt] = *(const h8v*)(bp + kt*512);
                }
                float bi2 = b2[net*D2 + nt*16 + m];
                f4v a0e = {bi2, bi2, bi2, bi2}, a1e = a0e;
                f4v a0o = {0.f,0.f,0.f,0.f},   a1o = a0o;
                #pragma unroll
                for (int kt = 0; kt < 5; kt++){
                    if ((kt & 1) == 0){
                        a0e = __builtin_amdgcn_mfma_f32_16x16x32_f16(A2[0][kt], Bb[cur][kt], a0e, 0, 0, 0);
                        a1e = __builtin_amdgcn_mfma_f32_16x16x32_f16(A2[1][kt], Bb[cur][kt], a1e, 0, 0, 0);
                    } else {
                        a0o = __builtin_amdgcn_mfma_f32_16x16x32_f16(A2[0][kt], Bb[cur][kt], a0o, 0, 0, 0);
                        a1o = __builtin_amdgcn_mfma_f32_16x16x32_f16(A2[1][kt], Bb[cur][kt], a1o, 0, 0, 0);
                    }
                }
                f4v a0 = a0e + a0o, a1 = a1e + a1o;
                int colB = (nt*16 + m)*2;
                #pragma unroll
                for (int r = 0; r < 4; r++){
                    *(unsigned short*)(xb + swzb(quad*4 + r,      colB, 256)) = f2h(celu01(a0[r]));
                    *(unsigned short*)(xb + swzb(16 + quad*4 + r, colB, 256)) = f2h(celu01(a1[r]));
                }
            }
        }

        // ---------- layer 3 + 4 fused: X2 [K=128] -> per-lane partial energies ----------
        {
            h8v A3[2][4];
            #pragma unroll
            for (int mt = 0; mt < 2; mt++)
                #pragma unroll
                for (int kt = 0; kt < 4; kt++)
                    A3[mt][kt] = *(const h8v*)(xb + swzb(mt*16 + m, (kt*32 + quad*8)*2, 256));
            const unsigned short* wf = W3b + (size_t)net * (D2*D3) + lane*8;
            const float* w4 = W4 + net * D3;
            h8v Bb[2][4];
            #pragma unroll
            for (int kt = 0; kt < 4; kt++) Bb[0][kt] = *(const h8v*)(wf + kt*512);
            #pragma unroll
            for (int nt = 0; nt < 6; nt++){
                int cur = nt & 1, nxt = cur ^ 1;
                if (nt < 5){
                    const unsigned short* bp = wf + (nt+1)*2048;
                    #pragma unroll
                    for (int kt = 0; kt < 4; kt++) Bb[nxt][kt] = *(const h8v*)(bp + kt*512);
                }
                float bi3 = b3[net*D3 + nt*16 + m];
                f4v a0e = {bi3, bi3, bi3, bi3}, a1e = a0e;
                f4v a0o = {0.f,0.f,0.f,0.f},   a1o = a0o;
                #pragma unroll
                for (int kt = 0; kt < 4; kt += 2){
                    a0e = __builtin_amdgcn_mfma_f32_16x16x32_f16(A3[0][kt],   Bb[cur][kt],   a0e, 0, 0, 0);
                    a1e = __builtin_amdgcn_mfma_f32_16x16x32_f16(A3[1][kt],   Bb[cur][kt],   a1e, 0, 0, 0);
                    a0o = __builtin_amdgcn_mfma_f32_16x16x32_f16(A3[0][kt+1], Bb[cur][kt+1], a0o, 0, 0, 0);
                    a1o = __builtin_amdgcn_mfma_f32_16x16x32_f16(A3[1][kt+1], Bb[cur][kt+1], a1o, 0, 0, 0);
                }
                f4v a0 = a0e + a0o, a1 = a1e + a1o;
                float w = w4[nt*16 + m];
                // deferred reduction: per-lane fmaf only; full reduce once at end
                #pragma unroll
                for (int r = 0; r < 4; r++){
                    e0[r] = fmaf(celu01(a0[r]), w, e0[r]);
                    e1[r] = fmaf(celu01(a1[r]), w, e1[r]);
                }
            }
        }
    }

    // ---- final: mask padded atoms, single 6-shuffle wave reduction, one atomic ----
    {
        float tot = 0.f;
        #pragma unroll
        for (int r = 0; r < 4; r++){
            tot += (quad*4 + r      < nValid) ? e0[r] : 0.f;
            tot += (16 + quad*4 + r < nValid) ? e1[r] : 0.f;
        }
        tot += __shfl_xor(tot, 1, 64);
        tot += __shfl_xor(tot, 2, 64);
        tot += __shfl_xor(tot, 4, 64);
        tot += __shfl_xor(tot, 8, 64);
        tot += __shfl_xor(tot, 16, 64);
        tot += __shfl_xor(tot, 32, 64);
        if (lane == 0 && nValid > 0){
            float sb4 = 0.f;
            for (int e = eBeg; e < eEnd; e++) sb4 += b4[s*NE + e];
            atomicAdd(out, (tot + (float)nValid * sb4) * 0.125f);
        }
    }
}

extern "C" void kernel_launch(void* const* d_in, const int* in_sizes, int n_in,
                              void* d_out, int out_size, void* d_ws, size_t ws_size,
                              hipStream_t stream){
    const float* aev     = (const float*)d_in[0];
    const int*   species = (const int*)  d_in[1];
    const float* W1 = (const float*)d_in[2];
    const float* b1 = (const float*)d_in[3];
    const float* W2 = (const float*)d_in[4];
    const float* b2 = (const float*)d_in[5];
    const float* W3 = (const float*)d_in[6];
    const float* b3 = (const float*)d_in[7];
    const float* W4 = (const float*)d_in[8];
    const float* b4 = (const float*)d_in[9];
    float* out = (float*)d_out;

    int* hdr = (int*)d_ws;
    int* idx = (int*)((char*)d_ws + IDX_OFF_B);
    unsigned short* W1b = (unsigned short*)((char*)d_ws + W1B_OFF);
    unsigned short* W2b = (unsigned short*)((char*)d_ws + W2B_OFF);
    unsigned short* W3b = (unsigned short*)((char*)d_ws + W3B_OFF);

    k_init <<<1, 64, 0, stream>>>(hdr, out);
    k_prep <<<SCB + CVB, 256, 0, stream>>>(species, hdr, idx, W1, W2, W3, W1b, W2b, W3b);
    k_mlp  <<<GRID_MLP, 256, 0, stream>>>(aev, hdr, idx, W1b, W2b, W3b,
                                          b1, b2, b3, W4, b4, out);
}

// Round 7
// 502.481 us; speedup vs baseline: 2.1465x; 2.1465x over previous
//
#include <hip/hip_runtime.h>
#include <stdint.h>

#define N_ATOMS 100000
#define NS 4
#define NE 8
#define D0 384
#define D1 160
#define D2 128
#define D3 96
#define TW 32                                 // atoms per wave tile
#define BUCKET_CAP 32768

// ---- workspace layout (bytes) ----
#define IDX_OFF_B 256
#define IDX_CAP (NS*BUCKET_CAP)               // 131072 ints
#define W1B_OFF (IDX_OFF_B + IDX_CAP*4)
#define W1_TOT (NS*NE*D0*D1)
#define W2_TOT (NS*NE*D1*D2)
#define W3_TOT (NS*NE*D2*D3)
#define W2B_OFF (W1B_OFF + W1_TOT*2)
#define W3B_OFF (W2B_OFF + W2_TOT*2)

// LDS strides (halves) — measured 0 bank conflicts with these (R2).
#define S1STR 172
#define S2STR 140

// residency plan: 3 blocks/CU (44032 B LDS each) * 256 CU * 4 waves = 3072
// full-tile wave slots in one phase. Tiles beyond 3072 (max total = 3128)
// run as single-e units spread over 112 tail blocks.
#define P1TILES 3072
#define P1BLOCKS 768
#define MAXTILES 3128
#define TAILBLOCKS 112                        // 112*4 = 448 >= 56*8 units
#define GRID_MLP (P1BLOCKS + TAILBLOCKS)

typedef __attribute__((ext_vector_type(8))) _Float16 h8v;
typedef __attribute__((ext_vector_type(4))) float f4v;

__device__ __forceinline__ unsigned short f2h(float x){
    _Float16 h = (_Float16)x;
    return *(unsigned short*)&h;
}

// jax.nn.celu(x, 0.1) = x>0 ? x : 0.1*expm1(x/0.1)
__device__ __forceinline__ float celu01(float v){
    return v > 0.f ? v : 0.1f * (__expf(fminf(v, 0.f) * 10.f) - 1.f);
}

__global__ void k_init(int* hdr, float* out){
    int i = threadIdx.x;
    if (i < 32) hdr[i] = 0;
    if (i == 0) out[0] = 0.f;
}

__global__ __launch_bounds__(256) void k_scatter(const int* __restrict__ species,
                                                 int* __restrict__ hdr,
                                                 int* __restrict__ idx){
    __shared__ int lc[NS];
    __shared__ int lb[NS];
    int tid = threadIdx.x;
    if (tid < NS) lc[tid] = 0;
    __syncthreads();
    int i = blockIdx.x * 256 + tid;
    int s = 0, r = 0;
    bool valid = (i < N_ATOMS);
    if (valid){
        s = species[i];
        r = atomicAdd(&lc[s], 1);
    }
    __syncthreads();
    if (tid < NS) lb[tid] = atomicAdd(&hdr[tid], lc[tid]);
    __syncthreads();
    if (valid) idx[s * BUCKET_CAP + lb[s] + r] = i;
}

__global__ void k_scan(int* hdr){
    int tb = 0;
    hdr[16] = 0;
    for (int s = 0; s < 4; s++){
        int tiles = (hdr[s] + TW - 1) / TW;
        tb += tiles;
        hdr[17 + s] = tb;                     // hdr[20] = total tiles
    }
}

// W1..W3 fp32 -> fp16 in MFMA-B-fragment order: [net][nt][kt][lane][j]
__global__ void k_convert(const float* __restrict__ W1, const float* __restrict__ W2,
                          const float* __restrict__ W3,
                          unsigned short* __restrict__ W1b, unsigned short* __restrict__ W2b,
                          unsigned short* __restrict__ W3b){
    int i = blockIdx.x * blockDim.x + threadIdx.x;
    if (i < W1_TOT){
        int net = i / (D0*D1);
        int r   = i % (D0*D1);
        int j = r & 7, lane = (r >> 3) & 63, kt = (r >> 9) % 12, nt = r / 6144;
        int k = kt*32 + (lane >> 4)*8 + j;
        int n = nt*16 + (lane & 15);
        W1b[i] = f2h(W1[(net*D0 + k)*D1 + n]);
    } else if (i < W1_TOT + W2_TOT){
        int i2 = i - W1_TOT;
        int net = i2 / (D1*D2);
        int r   = i2 % (D1*D2);
        int j = r & 7, lane = (r >> 3) & 63, kt = (r >> 9) % 5, nt = r / 2560;
        int k = kt*32 + (lane >> 4)*8 + j;
        int n = nt*16 + (lane & 15);
        W2b[i2] = f2h(W2[(net*D1 + k)*D2 + n]);
    } else if (i < W1_TOT + W2_TOT + W3_TOT){
        int i3 = i - W1_TOT - W2_TOT;
        int net = i3 / (D2*D3);
        int r   = i3 % (D2*D3);
        int j = r & 7, lane = (r >> 3) & 63, kt = (r >> 9) % 4, nt = r / 2048;
        int k = kt*32 + (lane >> 4)*8 + j;
        int n = nt*16 + (lane & 15);
        W3b[i3] = f2h(W3[(net*D2 + k)*D3 + n]);
    }
}

// Barrier-free MLP (R2 body, measured 358us): one WAVE = one 32-atom tile
// (full e-loop) or one (tile,e) unit (tail). X1/X2 union one 11008 B per-wave
// LDS region (layer l+1 fully reads layer l into regs before overwriting).
// B fragments stream global->reg with next-nt double-buffer. Pad-strides
// 172/140: measured 0 LDS bank conflicts. Plain (cached) loads everywhere:
// NT loads measured 4x HBM fetch amplification + lost L3 reuse (R6).
// NOTE __launch_bounds__(256,2) is load-bearing: min-waves>=3 -> 84 VGPR ->
// 164 MB scratch spill (measured R1/R4).
// R7 delta vs R2: bias/W4 loads prefetched one nt ahead (they fed the
// accumulator init directly -> ~200-400 cyc stall at EVERY nt iteration).
__global__ __launch_bounds__(256, 2) void k_mlp(
    const float* __restrict__ aev, const int* __restrict__ hdr, const int* __restrict__ idx,
    const unsigned short* __restrict__ W1b, const unsigned short* __restrict__ W2b,
    const unsigned short* __restrict__ W3b,
    const float* __restrict__ b1, const float* __restrict__ b2, const float* __restrict__ b3,
    const float* __restrict__ W4, const float* __restrict__ b4, float* __restrict__ out)
{
    __shared__ __align__(16) unsigned short sBuf[4][TW*S1STR];   // 44032 B

    int tid = threadIdx.x;
    int lane = tid & 63, wid = tid >> 6;
    int total = hdr[20];
    int bi = blockIdx.x;
    int tileId, eBeg, eEnd;
    if (bi < P1BLOCKS){
        // XCD-chunked: each of 8 XCDs owns a contiguous 384-tile range;
        // the 4 waves of a block take 4 consecutive tiles.
        tileId = (bi & 7) * (P1TILES/8) + (bi >> 3) * 4 + wid;
        eBeg = 0; eEnd = NE;
    } else {
        int u = (bi - P1BLOCKS) * 4 + wid;
        tileId = P1TILES + (u >> 3);
        eBeg = u & 7; eEnd = eBeg + 1;
    }
    if (tileId >= total) return;

    int s = 0;
    while (s < 3 && tileId >= hdr[17 + s]) s++;
    int t       = tileId - hdr[16 + s];
    int count   = hdr[s];
    int rowBase = t * TW;
    const int* myIdx = idx + s * BUCKET_CAP + rowBase;
    int nValid = count - rowBase; if (nValid > TW) nValid = TW;

    int m = lane & 15, quad = lane >> 4;
    unsigned short (*X1)[S1STR] = (unsigned short (*)[S1STR])sBuf[wid];
    unsigned short (*X2)[S2STR] = (unsigned short (*)[S2STR])sBuf[wid];

    // ---- layer-1 A fragments from global AEV (fp32->fp16), e-invariant ----
    h8v A1[2][12];
    #pragma unroll
    for (int mt = 0; mt < 2; mt++){
        int slot = mt*16 + m;
        int atom = myIdx[(slot < nValid) ? slot : 0];         // guarded pad
        if ((unsigned)atom >= N_ATOMS) atom = 0;              // clamp stale tail reads
        const float* ap = aev + (size_t)atom * D0 + quad*8;
        #pragma unroll
        for (int kt = 0; kt < 12; kt++){
            float4 u = *(const float4*)(ap + kt*32);
            float4 v = *(const float4*)(ap + kt*32 + 4);
            h8v f;
            f[0] = (_Float16)u.x; f[1] = (_Float16)u.y; f[2] = (_Float16)u.z; f[3] = (_Float16)u.w;
            f[4] = (_Float16)v.x; f[5] = (_Float16)v.y; f[6] = (_Float16)v.z; f[7] = (_Float16)v.w;
            A1[mt][kt] = f;
        }
    }

    float e0[4] = {0.f,0.f,0.f,0.f};
    float e1[4] = {0.f,0.f,0.f,0.f};

    #pragma unroll 1
    for (int e = eBeg; e < eEnd; e++){
        int net = s * NE + e;

        // ---------- layer 1: A1(regs) [K=384] -> X1 [N=160] ----------
        // full next-nt B prefetch (12 frags in flight) + even/odd acc chains
        {
            const unsigned short* wf = W1b + (size_t)net * (D0*D1) + lane*8;
            float bc = b1[net*D1 + m];                        // bias for nt=0
            h8v Bb[2][12];
            #pragma unroll
            for (int kt = 0; kt < 12; kt++) Bb[0][kt] = *(const h8v*)(wf + kt*512);
            #pragma unroll
            for (int nt = 0; nt < 10; nt++){
                int cur = nt & 1, nxt = cur ^ 1;
                float bn = 0.f;
                if (nt < 9){
                    const unsigned short* bp = wf + (nt+1)*6144;
                    #pragma unroll
                    for (int kt = 0; kt < 12; kt++) Bb[nxt][kt] = *(const h8v*)(bp + kt*512);
                    bn = b1[net*D1 + (nt+1)*16 + m];          // prefetch next bias
                }
                f4v a0e = {bc, bc, bc, bc}, a1e = a0e;
                f4v a0o = {0.f,0.f,0.f,0.f}, a1o = a0o;
                #pragma unroll
                for (int kt = 0; kt < 12; kt += 2){
                    a0e = __builtin_amdgcn_mfma_f32_16x16x32_f16(A1[0][kt],   Bb[cur][kt],   a0e, 0, 0, 0);
                    a1e = __builtin_amdgcn_mfma_f32_16x16x32_f16(A1[1][kt],   Bb[cur][kt],   a1e, 0, 0, 0);
                    a0o = __builtin_amdgcn_mfma_f32_16x16x32_f16(A1[0][kt+1], Bb[cur][kt+1], a0o, 0, 0, 0);
                    a1o = __builtin_amdgcn_mfma_f32_16x16x32_f16(A1[1][kt+1], Bb[cur][kt+1], a1o, 0, 0, 0);
                }
                f4v a0 = a0e + a0o, a1 = a1e + a1o;
                #pragma unroll
                for (int r = 0; r < 4; r++){
                    X1[quad*4 + r][nt*16 + m]      = f2h(celu01(a0[r]));
                    X1[16 + quad*4 + r][nt*16 + m] = f2h(celu01(a1[r]));
                }
                bc = bn;
            }
        }

        // ---------- layer 2: X1 [K=160] -> X2 [N=128] ----------
        {
            h8v A2[2][5];
            #pragma unroll
            for (int mt = 0; mt < 2; mt++)
                #pragma unroll
                for (int kt = 0; kt < 5; kt++)
                    A2[mt][kt] = *(const h8v*)&X1[mt*16 + m][kt*32 + quad*8];
            const unsigned short* wf = W2b + (size_t)net * (D1*D2) + lane*8;
            float bc = b2[net*D2 + m];
            h8v Bb[2][5];
            #pragma unroll
            for (int kt = 0; kt < 5; kt++) Bb[0][kt] = *(const h8v*)(wf + kt*512);
            #pragma unroll
            for (int nt = 0; nt < 8; nt++){
                int cur = nt & 1, nxt = cur ^ 1;
                float bn = 0.f;
                if (nt < 7){
                    const unsigned short* bp = wf + (nt+1)*2560;
                    #pragma unroll
                    for (int kt = 0; kt < 5; kt++) Bb[nxt][kt] = *(const h8v*)(bp + kt*512);
                    bn = b2[net*D2 + (nt+1)*16 + m];
                }
                f4v a0e = {bc, bc, bc, bc}, a1e = a0e;
                f4v a0o = {0.f,0.f,0.f,0.f}, a1o = a0o;
                #pragma unroll
                for (int kt = 0; kt < 5; kt++){
                    if ((kt & 1) == 0){
                        a0e = __builtin_amdgcn_mfma_f32_16x16x32_f16(A2[0][kt], Bb[cur][kt], a0e, 0, 0, 0);
                        a1e = __builtin_amdgcn_mfma_f32_16x16x32_f16(A2[1][kt], Bb[cur][kt], a1e, 0, 0, 0);
                    } else {
                        a0o = __builtin_amdgcn_mfma_f32_16x16x32_f16(A2[0][kt], Bb[cur][kt], a0o, 0, 0, 0);
                        a1o = __builtin_amdgcn_mfma_f32_16x16x32_f16(A2[1][kt], Bb[cur][kt], a1o, 0, 0, 0);
                    }
                }
                f4v a0 = a0e + a0o, a1 = a1e + a1o;
                #pragma unroll
                for (int r = 0; r < 4; r++){
                    X2[quad*4 + r][nt*16 + m]      = f2h(celu01(a0[r]));
                    X2[16 + quad*4 + r][nt*16 + m] = f2h(celu01(a1[r]));
                }
                bc = bn;
            }
        }

        // ---------- layer 3 + 4 fused: X2 [K=128] -> per-lane partial energies ----------
        {
            h8v A3[2][4];
            #pragma unroll
            for (int mt = 0; mt < 2; mt++)
                #pragma unroll
                for (int kt = 0; kt < 4; kt++)
                    A3[mt][kt] = *(const h8v*)&X2[mt*16 + m][kt*32 + quad*8];
            const unsigned short* wf = W3b + (size_t)net * (D2*D3) + lane*8;
            const float* w4 = W4 + net * D3;
            float bc = b3[net*D3 + m];
            float wc = w4[m];
            h8v Bb[2][4];
            #pragma unroll
            for (int kt = 0; kt < 4; kt++) Bb[0][kt] = *(const h8v*)(wf + kt*512);
            #pragma unroll
            for (int nt = 0; nt < 6; nt++){
                int cur = nt & 1, nxt = cur ^ 1;
                float bn = 0.f, wn = 0.f;
                if (nt < 5){
                    const unsigned short* bp = wf + (nt+1)*2048;
                    #pragma unroll
                    for (int kt = 0; kt < 4; kt++) Bb[nxt][kt] = *(const h8v*)(bp + kt*512);
                    bn = b3[net*D3 + (nt+1)*16 + m];
                    wn = w4[(nt+1)*16 + m];
                }
                f4v a0e = {bc, bc, bc, bc}, a1e = a0e;
                f4v a0o = {0.f,0.f,0.f,0.f}, a1o = a0o;
                #pragma unroll
                for (int kt = 0; kt < 4; kt += 2){
                    a0e = __builtin_amdgcn_mfma_f32_16x16x32_f16(A3[0][kt],   Bb[cur][kt],   a0e, 0, 0, 0);
                    a1e = __builtin_amdgcn_mfma_f32_16x16x32_f16(A3[1][kt],   Bb[cur][kt],   a1e, 0, 0, 0);
                    a0o = __builtin_amdgcn_mfma_f32_16x16x32_f16(A3[0][kt+1], Bb[cur][kt+1], a0o, 0, 0, 0);
                    a1o = __builtin_amdgcn_mfma_f32_16x16x32_f16(A3[1][kt+1], Bb[cur][kt+1], a1o, 0, 0, 0);
                }
                f4v a0 = a0e + a0o, a1 = a1e + a1o;
                // deferred reduction: per-lane fmaf only; full reduce once at end
                #pragma unroll
                for (int r = 0; r < 4; r++){
                    e0[r] = fmaf(celu01(a0[r]), wc, e0[r]);
                    e1[r] = fmaf(celu01(a1[r]), wc, e1[r]);
                }
                bc = bn; wc = wn;
            }
        }
    }

    // ---- final: mask padded atoms, single 6-shuffle wave reduction, one atomic ----
    {
        float tot = 0.f;
        #pragma unroll
        for (int r = 0; r < 4; r++){
            tot += (quad*4 + r      < nValid) ? e0[r] : 0.f;
            tot += (16 + quad*4 + r < nValid) ? e1[r] : 0.f;
        }
        tot += __shfl_xor(tot, 1, 64);
        tot += __shfl_xor(tot, 2, 64);
        tot += __shfl_xor(tot, 4, 64);
        tot += __shfl_xor(tot, 8, 64);
        tot += __shfl_xor(tot, 16, 64);
        tot += __shfl_xor(tot, 32, 64);
        if (lane == 0 && nValid > 0){
            float sb4 = 0.f;
            for (int e = eBeg; e < eEnd; e++) sb4 += b4[s*NE + e];
            atomicAdd(out, (tot + (float)nValid * sb4) * 0.125f);
        }
    }
}

extern "C" void kernel_launch(void* const* d_in, const int* in_sizes, int n_in,
                              void* d_out, int out_size, void* d_ws, size_t ws_size,
                              hipStream_t stream){
    const float* aev     = (const float*)d_in[0];
    const int*   species = (const int*)  d_in[1];
    const float* W1 = (const float*)d_in[2];
    const float* b1 = (const float*)d_in[3];
    const float* W2 = (const float*)d_in[4];
    const float* b2 = (const float*)d_in[5];
    const float* W3 = (const float*)d_in[6];
    const float* b3 = (const float*)d_in[7];
    const float* W4 = (const float*)d_in[8];
    const float* b4 = (const float*)d_in[9];
    float* out = (float*)d_out;

    int* hdr = (int*)d_ws;
    int* idx = (int*)((char*)d_ws + IDX_OFF_B);
    unsigned short* W1b = (unsigned short*)((char*)d_ws + W1B_OFF);
    unsigned short* W2b = (unsigned short*)((char*)d_ws + W2B_OFF);
    unsigned short* W3b = (unsigned short*)((char*)d_ws + W3B_OFF);

    k_init   <<<1, 64, 0, stream>>>(hdr, out);
    k_scatter<<<(N_ATOMS + 255)/256, 256, 0, stream>>>(species, hdr, idx);
    k_scan   <<<1, 1, 0, stream>>>(hdr);
    int convTot = W1_TOT + W2_TOT + W3_TOT;
    k_convert<<<(convTot + 255)/256, 256, 0, stream>>>(W1, W2, W3, W1b, W2b, W3b);
    k_mlp    <<<GRID_MLP, 256, 0, stream>>>(aev, hdr, idx, W1b, W2b, W3b,
                                            b1, b2, b3, W4, b4, out);
}

// Round 8
// 502.036 us; speedup vs baseline: 2.1484x; 1.0009x over previous
//
#include <hip/hip_runtime.h>
#include <stdint.h>

#define N_ATOMS 100000
#define NS 4
#define NE 8
#define D0 384
#define D1 160
#define D2 128
#define D3 96
#define TW 32                                 // atoms per wave tile
#define BUCKET_CAP 32768

// ---- workspace layout (bytes) ----
#define IDX_OFF_B 256
#define IDX_CAP (NS*BUCKET_CAP)               // 131072 ints
#define W1B_OFF (IDX_OFF_B + IDX_CAP*4)
#define W1_TOT (NS*NE*D0*D1)
#define W2_TOT (NS*NE*D1*D2)
#define W3_TOT (NS*NE*D2*D3)
#define W2B_OFF (W1B_OFF + W1_TOT*2)
#define W3B_OFF (W2B_OFF + W2_TOT*2)

// LDS strides (halves) — measured 0 bank conflicts with these (R2/R7).
#define S1STR 172
#define S2STR 140

// residency plan: 768 phase-1 blocks (4 waves * 4 consecutive same-species
// tiles each) + 112 tail blocks running leftover tiles as (tile, e) units.
#define P1TILES 3072
#define P1BLOCKS 768
#define TAILBLOCKS 112                        // 112*4 = 448 = 56*8 units
#define GRID_MLP (P1BLOCKS + TAILBLOCKS)

typedef __attribute__((ext_vector_type(8))) _Float16 h8v;
typedef __attribute__((ext_vector_type(4))) float f4v;

__device__ __forceinline__ unsigned short f2h(float x){
    _Float16 h = (_Float16)x;
    return *(unsigned short*)&h;
}

// jax.nn.celu(x, 0.1) = x>0 ? x : 0.1*expm1(x/0.1)
__device__ __forceinline__ float celu01(float v){
    return v > 0.f ? v : 0.1f * (__expf(fminf(v, 0.f) * 10.f) - 1.f);
}

__global__ void k_init(int* hdr, float* out){
    int i = threadIdx.x;
    if (i < 32) hdr[i] = 0;
    if (i == 0) out[0] = 0.f;
}

__global__ __launch_bounds__(256) void k_scatter(const int* __restrict__ species,
                                                 int* __restrict__ hdr,
                                                 int* __restrict__ idx){
    __shared__ int lc[NS];
    __shared__ int lb[NS];
    int tid = threadIdx.x;
    if (tid < NS) lc[tid] = 0;
    __syncthreads();
    int i = blockIdx.x * 256 + tid;
    int s = 0, r = 0;
    bool valid = (i < N_ATOMS);
    if (valid){
        s = species[i];
        r = atomicAdd(&lc[s], 1);
    }
    __syncthreads();
    if (tid < NS) lb[tid] = atomicAdd(&hdr[tid], lc[tid]);
    __syncthreads();
    if (valid) idx[s * BUCKET_CAP + lb[s] + r] = i;
}

// W1..W3 fp32 -> fp16 in MFMA-B-fragment order: [net][nt][kt][lane][j]
__global__ void k_convert(const float* __restrict__ W1, const float* __restrict__ W2,
                          const float* __restrict__ W3,
                          unsigned short* __restrict__ W1b, unsigned short* __restrict__ W2b,
                          unsigned short* __restrict__ W3b){
    int i = blockIdx.x * blockDim.x + threadIdx.x;
    if (i < W1_TOT){
        int net = i / (D0*D1);
        int r   = i % (D0*D1);
        int j = r & 7, lane = (r >> 3) & 63, kt = (r >> 9) % 12, nt = r / 6144;
        int k = kt*32 + (lane >> 4)*8 + j;
        int n = nt*16 + (lane & 15);
        W1b[i] = f2h(W1[(net*D0 + k)*D1 + n]);
    } else if (i < W1_TOT + W2_TOT){
        int i2 = i - W1_TOT;
        int net = i2 / (D1*D2);
        int r   = i2 % (D1*D2);
        int j = r & 7, lane = (r >> 3) & 63, kt = (r >> 9) % 5, nt = r / 2560;
        int k = kt*32 + (lane >> 4)*8 + j;
        int n = nt*16 + (lane & 15);
        W2b[i2] = f2h(W2[(net*D1 + k)*D2 + n]);
    } else if (i < W1_TOT + W2_TOT + W3_TOT){
        int i3 = i - W1_TOT - W2_TOT;
        int net = i3 / (D2*D3);
        int r   = i3 % (D2*D3);
        int j = r & 7, lane = (r >> 3) & 63, kt = (r >> 9) % 4, nt = r / 2048;
        int k = kt*32 + (lane >> 4)*8 + j;
        int n = nt*16 + (lane & 15);
        W3b[i3] = f2h(W3[(net*D2 + k)*D3 + n]);
    }
}

// Barrier-LIGHT MLP (R7 body + 1 barrier per e): one WAVE = one 32-atom tile.
// The 4 waves of a phase-1 block hold 4 consecutive SAME-SPECIES tiles, so at
// equal e they read byte-identical weight addresses. One __syncthreads per e
// (8 total, ~2us) keeps them converged so wave 0's L2 fills serve waves 1-3
// from L1 -> ~4x less L2 weight traffic + L1-latency loads. (R5's 272-barrier
// lockstep version proved the traffic cut but barrier drains ate the gain.)
// Pad-strides 172/140: measured 0 LDS bank conflicts. Plain cached loads (NT
// loads measured 4x HBM amplification, R6). __launch_bounds__(256,2) is
// load-bearing: min-waves>=3 -> 84 VGPR -> 164 MB scratch spill (R1/R4).
// Bias/W4 prefetched one nt ahead (R7, -22us).
// Tail waves never early-return: clamped to nValid=0 with a uniform 1-trip
// e-loop so the per-e barrier cannot deadlock.
__global__ __launch_bounds__(256, 2) void k_mlp(
    const float* __restrict__ aev, const int* __restrict__ hdr, const int* __restrict__ idx,
    const unsigned short* __restrict__ W1b, const unsigned short* __restrict__ W2b,
    const unsigned short* __restrict__ W3b,
    const float* __restrict__ b1, const float* __restrict__ b2, const float* __restrict__ b3,
    const float* __restrict__ W4, const float* __restrict__ b4, float* __restrict__ out)
{
    __shared__ __align__(16) unsigned short sBuf[4][TW*S1STR];   // 44032 B

    int tid = threadIdx.x;
    int lane = tid & 63, wid = tid >> 6;

    // ---- in-register scan (k_scan folded): tile prefixes from hdr[0..3] ----
    int c0 = hdr[0], c1 = hdr[1], c2 = hdr[2], c3 = hdr[3];
    int t0 = (c0 + 31) >> 5, t1 = (c1 + 31) >> 5, t2 = (c2 + 31) >> 5;
    int q1 = t0, q2 = q1 + t1, q3 = q2 + t2, total = q3 + ((c3 + 31) >> 5);

    int bi = blockIdx.x;
    int tileId, eBeg, eEnd;
    bool live = true;
    if (bi < P1BLOCKS){
        // XCD-chunked: each of 8 XCDs owns a contiguous 384-tile range;
        // the 4 waves of a block take 4 consecutive tiles (same species).
        tileId = (bi & 7) * (P1TILES/8) + (bi >> 3) * 4 + wid;   // < 3072 < total
        eBeg = 0; eEnd = NE;
    } else {
        int u = (bi - P1BLOCKS) * 4 + wid;
        tileId = P1TILES + (u >> 3);
        eBeg = u & 7; eEnd = eBeg + 1;                           // uniform 1 trip
        if (tileId >= total){ tileId = total - 1; live = false; }
    }

    int s = (tileId >= q3) ? 3 : (tileId >= q2) ? 2 : (tileId >= q1) ? 1 : 0;
    int tb = (s == 0) ? 0 : (s == 1) ? q1 : (s == 2) ? q2 : q3;
    int cs = (s == 0) ? c0 : (s == 1) ? c1 : (s == 2) ? c2 : c3;
    int rowBase = (tileId - tb) * TW;
    const int* myIdx = idx + s * BUCKET_CAP + rowBase;
    int nValid = cs - rowBase; if (nValid > TW) nValid = TW; if (nValid < 0) nValid = 0;
    if (!live) nValid = 0;

    int m = lane & 15, quad = lane >> 4;
    unsigned short (*X1)[S1STR] = (unsigned short (*)[S1STR])sBuf[wid];
    unsigned short (*X2)[S2STR] = (unsigned short (*)[S2STR])sBuf[wid];

    // ---- layer-1 A fragments from global AEV (fp32->fp16), e-invariant ----
    h8v A1[2][12];
    #pragma unroll
    for (int mt = 0; mt < 2; mt++){
        int slot = mt*16 + m;
        int atom = myIdx[(slot < nValid) ? slot : 0];         // guarded pad
        if ((unsigned)atom >= N_ATOMS) atom = 0;              // clamp stale reads
        const float* ap = aev + (size_t)atom * D0 + quad*8;
        #pragma unroll
        for (int kt = 0; kt < 12; kt++){
            float4 u = *(const float4*)(ap + kt*32);
            float4 v = *(const float4*)(ap + kt*32 + 4);
            h8v f;
            f[0] = (_Float16)u.x; f[1] = (_Float16)u.y; f[2] = (_Float16)u.z; f[3] = (_Float16)u.w;
            f[4] = (_Float16)v.x; f[5] = (_Float16)v.y; f[6] = (_Float16)v.z; f[7] = (_Float16)v.w;
            A1[mt][kt] = f;
        }
    }

    float e0[4] = {0.f,0.f,0.f,0.f};
    float e1[4] = {0.f,0.f,0.f,0.f};

    #pragma unroll 1
    for (int e = eBeg; e < eEnd; e++){
        __syncthreads();                      // converge the 4 waves -> L1 sharing
        int net = s * NE + e;

        // ---------- layer 1: A1(regs) [K=384] -> X1 [N=160] ----------
        // full next-nt B prefetch (12 frags in flight) + even/odd acc chains
        {
            const unsigned short* wf = W1b + (size_t)net * (D0*D1) + lane*8;
            float bc = b1[net*D1 + m];                        // bias for nt=0
            h8v Bb[2][12];
            #pragma unroll
            for (int kt = 0; kt < 12; kt++) Bb[0][kt] = *(const h8v*)(wf + kt*512);
            #pragma unroll
            for (int nt = 0; nt < 10; nt++){
                int cur = nt & 1, nxt = cur ^ 1;
                float bn = 0.f;
                if (nt < 9){
                    const unsigned short* bp = wf + (nt+1)*6144;
                    #pragma unroll
                    for (int kt = 0; kt < 12; kt++) Bb[nxt][kt] = *(const h8v*)(bp + kt*512);
                    bn = b1[net*D1 + (nt+1)*16 + m];          // prefetch next bias
                }
                f4v a0e = {bc, bc, bc, bc}, a1e = a0e;
                f4v a0o = {0.f,0.f,0.f,0.f}, a1o = a0o;
                #pragma unroll
                for (int kt = 0; kt < 12; kt += 2){
                    a0e = __builtin_amdgcn_mfma_f32_16x16x32_f16(A1[0][kt],   Bb[cur][kt],   a0e, 0, 0, 0);
                    a1e = __builtin_amdgcn_mfma_f32_16x16x32_f16(A1[1][kt],   Bb[cur][kt],   a1e, 0, 0, 0);
                    a0o = __builtin_amdgcn_mfma_f32_16x16x32_f16(A1[0][kt+1], Bb[cur][kt+1], a0o, 0, 0, 0);
                    a1o = __builtin_amdgcn_mfma_f32_16x16x32_f16(A1[1][kt+1], Bb[cur][kt+1], a1o, 0, 0, 0);
                }
                f4v a0 = a0e + a0o, a1 = a1e + a1o;
                #pragma unroll
                for (int r = 0; r < 4; r++){
                    X1[quad*4 + r][nt*16 + m]      = f2h(celu01(a0[r]));
                    X1[16 + quad*4 + r][nt*16 + m] = f2h(celu01(a1[r]));
                }
                bc = bn;
            }
        }

        // ---------- layer 2: X1 [K=160] -> X2 [N=128] ----------
        {
            h8v A2[2][5];
            #pragma unroll
            for (int mt = 0; mt < 2; mt++)
                #pragma unroll
                for (int kt = 0; kt < 5; kt++)
                    A2[mt][kt] = *(const h8v*)&X1[mt*16 + m][kt*32 + quad*8];
            const unsigned short* wf = W2b + (size_t)net * (D1*D2) + lane*8;
            float bc = b2[net*D2 + m];
            h8v Bb[2][5];
            #pragma unroll
            for (int kt = 0; kt < 5; kt++) Bb[0][kt] = *(const h8v*)(wf + kt*512);
            #pragma unroll
            for (int nt = 0; nt < 8; nt++){
                int cur = nt & 1, nxt = cur ^ 1;
                float bn = 0.f;
                if (nt < 7){
                    const unsigned short* bp = wf + (nt+1)*2560;
                    #pragma unroll
                    for (int kt = 0; kt < 5; kt++) Bb[nxt][kt] = *(const h8v*)(bp + kt*512);
                    bn = b2[net*D2 + (nt+1)*16 + m];
                }
                f4v a0e = {bc, bc, bc, bc}, a1e = a0e;
                f4v a0o = {0.f,0.f,0.f,0.f}, a1o = a0o;
                #pragma unroll
                for (int kt = 0; kt < 5; kt++){
                    if ((kt & 1) == 0){
                        a0e = __builtin_amdgcn_mfma_f32_16x16x32_f16(A2[0][kt], Bb[cur][kt], a0e, 0, 0, 0);
                        a1e = __builtin_amdgcn_mfma_f32_16x16x32_f16(A2[1][kt], Bb[cur][kt], a1e, 0, 0, 0);
                    } else {
                        a0o = __builtin_amdgcn_mfma_f32_16x16x32_f16(A2[0][kt], Bb[cur][kt], a0o, 0, 0, 0);
                        a1o = __builtin_amdgcn_mfma_f32_16x16x32_f16(A2[1][kt], Bb[cur][kt], a1o, 0, 0, 0);
                    }
                }
                f4v a0 = a0e + a0o, a1 = a1e + a1o;
                #pragma unroll
                for (int r = 0; r < 4; r++){
                    X2[quad*4 + r][nt*16 + m]      = f2h(celu01(a0[r]));
                    X2[16 + quad*4 + r][nt*16 + m] = f2h(celu01(a1[r]));
                }
                bc = bn;
            }
        }

        // ---------- layer 3 + 4 fused: X2 [K=128] -> per-lane partial energies ----------
        {
            h8v A3[2][4];
            #pragma unroll
            for (int mt = 0; mt < 2; mt++)
                #pragma unroll
                for (int kt = 0; kt < 4; kt++)
                    A3[mt][kt] = *(const h8v*)&X2[mt*16 + m][kt*32 + quad*8];
            const unsigned short* wf = W3b + (size_t)net * (D2*D3) + lane*8;
            const float* w4 = W4 + net * D3;
            float bc = b3[net*D3 + m];
            float wc = w4[m];
            h8v Bb[2][4];
            #pragma unroll
            for (int kt = 0; kt < 4; kt++) Bb[0][kt] = *(const h8v*)(wf + kt*512);
            #pragma unroll
            for (int nt = 0; nt < 6; nt++){
                int cur = nt & 1, nxt = cur ^ 1;
                float bn = 0.f, wn = 0.f;
                if (nt < 5){
                    const unsigned short* bp = wf + (nt+1)*2048;
                    #pragma unroll
                    for (int kt = 0; kt < 4; kt++) Bb[nxt][kt] = *(const h8v*)(bp + kt*512);
                    bn = b3[net*D3 + (nt+1)*16 + m];
                    wn = w4[(nt+1)*16 + m];
                }
                f4v a0e = {bc, bc, bc, bc}, a1e = a0e;
                f4v a0o = {0.f,0.f,0.f,0.f}, a1o = a0o;
                #pragma unroll
                for (int kt = 0; kt < 4; kt += 2){
                    a0e = __builtin_amdgcn_mfma_f32_16x16x32_f16(A3[0][kt],   Bb[cur][kt],   a0e, 0, 0, 0);
                    a1e = __builtin_amdgcn_mfma_f32_16x16x32_f16(A3[1][kt],   Bb[cur][kt],   a1e, 0, 0, 0);
                    a0o = __builtin_amdgcn_mfma_f32_16x16x32_f16(A3[0][kt+1], Bb[cur][kt+1], a0o, 0, 0, 0);
                    a1o = __builtin_amdgcn_mfma_f32_16x16x32_f16(A3[1][kt+1], Bb[cur][kt+1], a1o, 0, 0, 0);
                }
                f4v a0 = a0e + a0o, a1 = a1e + a1o;
                // deferred reduction: per-lane fmaf only; full reduce once at end
                #pragma unroll
                for (int r = 0; r < 4; r++){
                    e0[r] = fmaf(celu01(a0[r]), wc, e0[r]);
                    e1[r] = fmaf(celu01(a1[r]), wc, e1[r]);
                }
                bc = bn; wc = wn;
            }
        }
    }

    // ---- final: mask padded atoms, single 6-shuffle wave reduction, one atomic ----
    {
        float tot = 0.f;
        #pragma unroll
        for (int r = 0; r < 4; r++){
            tot += (quad*4 + r      < nValid) ? e0[r] : 0.f;
            tot += (16 + quad*4 + r < nValid) ? e1[r] : 0.f;
        }
        tot += __shfl_xor(tot, 1, 64);
        tot += __shfl_xor(tot, 2, 64);
        tot += __shfl_xor(tot, 4, 64);
        tot += __shfl_xor(tot, 8, 64);
        tot += __shfl_xor(tot, 16, 64);
        tot += __shfl_xor(tot, 32, 64);
        if (lane == 0 && nValid > 0){
            float sb4 = 0.f;
            for (int e = eBeg; e < eEnd; e++) sb4 += b4[s*NE + e];
            atomicAdd(out, (tot + (float)nValid * sb4) * 0.125f);
        }
    }
}

extern "C" void kernel_launch(void* const* d_in, const int* in_sizes, int n_in,
                              void* d_out, int out_size, void* d_ws, size_t ws_size,
                              hipStream_t stream){
    const float* aev     = (const float*)d_in[0];
    const int*   species = (const int*)  d_in[1];
    const float* W1 = (const float*)d_in[2];
    const float* b1 = (const float*)d_in[3];
    const float* W2 = (const float*)d_in[4];
    const float* b2 = (const float*)d_in[5];
    const float* W3 = (const float*)d_in[6];
    const float* b3 = (const float*)d_in[7];
    const float* W4 = (const float*)d_in[8];
    const float* b4 = (const float*)d_in[9];
    float* out = (float*)d_out;

    int* hdr = (int*)d_ws;
    int* idx = (int*)((char*)d_ws + IDX_OFF_B);
    unsigned short* W1b = (unsigned short*)((char*)d_ws + W1B_OFF);
    unsigned short* W2b = (unsigned short*)((char*)d_ws + W2B_OFF);
    unsigned short* W3b = (unsigned short*)((char*)d_ws + W3B_OFF);

    k_init   <<<1, 64, 0, stream>>>(hdr, out);
    k_scatter<<<(N_ATOMS + 255)/256, 256, 0, stream>>>(species, hdr, idx);
    int convTot = W1_TOT + W2_TOT + W3_TOT;
    k_convert<<<(convTot + 255)/256, 256, 0, stream>>>(W1, W2, W3, W1b, W2b, W3b);
    k_mlp    <<<GRID_MLP, 256, 0, stream>>>(aev, hdr, idx, W1b, W2b, W3b,
                                            b1, b2, b3, W4, b4, out);
}

// Round 9
// 483.851 us; speedup vs baseline: 2.2291x; 1.0376x over previous
//
#include <hip/hip_runtime.h>
#include <stdint.h>

#define N_ATOMS 100000
#define NS 4
#define NE 8
#define D0 384
#define D1 160
#define D2 128
#define D3 96
#define TW 32                                 // atoms per wave tile
#define BUCKET_CAP 32768

// ---- workspace layout (bytes) ----
#define IDX_OFF_B 256
#define IDX_CAP (NS*BUCKET_CAP)               // 131072 ints
#define W1B_OFF (IDX_OFF_B + IDX_CAP*4)
#define W1_TOT (NS*NE*D0*D1)
#define W2_TOT (NS*NE*D1*D2)
#define W3_TOT (NS*NE*D2*D3)
#define W2B_OFF (W1B_OFF + W1_TOT*2)
#define W3B_OFF (W2B_OFF + W2_TOT*2)

// LDS strides (halves) — 0 bank conflicts measured (R2/R7); b64-write pattern
// at these strides is uniform 4-accesses/bank (minimum) by construction.
#define S1STR 172
#define S2STR 140

// residency plan: 768 phase-1 blocks (4 waves * 4 consecutive same-species
// tiles each) + 112 tail blocks running leftover tiles as (tile, e) units.
#define P1TILES 3072
#define P1BLOCKS 768
#define TAILBLOCKS 112                        // 112*4 = 448 = 56*8 units
#define GRID_MLP (P1BLOCKS + TAILBLOCKS)

typedef __attribute__((ext_vector_type(8))) _Float16 h8v;
typedef __attribute__((ext_vector_type(4))) _Float16 h4v;
typedef __attribute__((ext_vector_type(4))) float f4v;

__device__ __forceinline__ unsigned short f2h(float x){
    _Float16 h = (_Float16)x;
    return *(unsigned short*)&h;
}

// jax.nn.celu(x, 0.1) = x>0 ? x : 0.1*expm1(x/0.1)
__device__ __forceinline__ float celu01(float v){
    return v > 0.f ? v : 0.1f * (__expf(fminf(v, 0.f) * 10.f) - 1.f);
}

__global__ void k_init(int* hdr, float* out){
    int i = threadIdx.x;
    if (i < 32) hdr[i] = 0;
    if (i == 0) out[0] = 0.f;
}

__global__ __launch_bounds__(256) void k_scatter(const int* __restrict__ species,
                                                 int* __restrict__ hdr,
                                                 int* __restrict__ idx){
    __shared__ int lc[NS];
    __shared__ int lb[NS];
    int tid = threadIdx.x;
    if (tid < NS) lc[tid] = 0;
    __syncthreads();
    int i = blockIdx.x * 256 + tid;
    int s = 0, r = 0;
    bool valid = (i < N_ATOMS);
    if (valid){
        s = species[i];
        r = atomicAdd(&lc[s], 1);
    }
    __syncthreads();
    if (tid < NS) lb[tid] = atomicAdd(&hdr[tid], lc[tid]);
    __syncthreads();
    if (valid) idx[s * BUCKET_CAP + lb[s] + r] = i;
}

// W1..W3 fp32 -> fp16 in MFMA fragment order: [net][nt][kt][lane][j].
// NOTE: A-frag and B-frag lane layouts are identical on gfx950
// (outer = lane&15, k = (lane>>4)*8+j), so this buffer serves as the
// A-operand of the swapped mfma(W, AEV) without any change.
__global__ void k_convert(const float* __restrict__ W1, const float* __restrict__ W2,
                          const float* __restrict__ W3,
                          unsigned short* __restrict__ W1b, unsigned short* __restrict__ W2b,
                          unsigned short* __restrict__ W3b){
    int i = blockIdx.x * blockDim.x + threadIdx.x;
    if (i < W1_TOT){
        int net = i / (D0*D1);
        int r   = i % (D0*D1);
        int j = r & 7, lane = (r >> 3) & 63, kt = (r >> 9) % 12, nt = r / 6144;
        int k = kt*32 + (lane >> 4)*8 + j;
        int n = nt*16 + (lane & 15);
        W1b[i] = f2h(W1[(net*D0 + k)*D1 + n]);
    } else if (i < W1_TOT + W2_TOT){
        int i2 = i - W1_TOT;
        int net = i2 / (D1*D2);
        int r   = i2 % (D1*D2);
        int j = r & 7, lane = (r >> 3) & 63, kt = (r >> 9) % 5, nt = r / 2560;
        int k = kt*32 + (lane >> 4)*8 + j;
        int n = nt*16 + (lane & 15);
        W2b[i2] = f2h(W2[(net*D1 + k)*D2 + n]);
    } else if (i < W1_TOT + W2_TOT + W3_TOT){
        int i3 = i - W1_TOT - W2_TOT;
        int net = i3 / (D2*D3);
        int r   = i3 % (D2*D3);
        int j = r & 7, lane = (r >> 3) & 63, kt = (r >> 9) % 4, nt = r / 2048;
        int k = kt*32 + (lane >> 4)*8 + j;
        int n = nt*16 + (lane & 15);
        W3b[i3] = f2h(W3[(net*D2 + k)*D3 + n]);
    }
}

// Barrier-free MLP, SWAPPED-OPERAND form: D[n][atom] = mfma(Wfrag, AEVfrag).
// Each lane holds 4 CONSECUTIVE n for a fixed atom (m / 16+m), so the
// epilogue packs one ds_write_b64 per atom-group (vs 8 ds_write_b16) and
// bias/W4 load as one float4 (vs 4 scalars). Reads, strides, prefetch depth,
// converter: byte-identical to the 336us R7 kernel.
// Proven-load-bearing facts: __launch_bounds__(256,2) (min-waves>=3 -> 84
// VGPR -> 164MB spill, R1/R4); plain cached loads (NT loads -> 4x HBM
// amplification, R6); no per-e barrier (R8: +7us); pad-strides 172/140
// (0 conflicts); bias prefetched 1 nt ahead (R7: -22us).
__global__ __launch_bounds__(256, 2) void k_mlp(
    const float* __restrict__ aev, const int* __restrict__ hdr, const int* __restrict__ idx,
    const unsigned short* __restrict__ W1b, const unsigned short* __restrict__ W2b,
    const unsigned short* __restrict__ W3b,
    const float* __restrict__ b1, const float* __restrict__ b2, const float* __restrict__ b3,
    const float* __restrict__ W4, const float* __restrict__ b4, float* __restrict__ out)
{
    __shared__ __align__(16) unsigned short sBuf[4][TW*S1STR];   // 44032 B

    int tid = threadIdx.x;
    int lane = tid & 63, wid = tid >> 6;

    // ---- in-register scan (k_scan folded): tile prefixes from hdr[0..3] ----
    int c0 = hdr[0], c1 = hdr[1], c2 = hdr[2], c3 = hdr[3];
    int t0 = (c0 + 31) >> 5, t1 = (c1 + 31) >> 5, t2 = (c2 + 31) >> 5;
    int q1 = t0, q2 = q1 + t1, q3 = q2 + t2, total = q3 + ((c3 + 31) >> 5);

    int bi = blockIdx.x;
    int tileId, eBeg, eEnd;
    if (bi < P1BLOCKS){
        // XCD-chunked: each of 8 XCDs owns a contiguous 384-tile range;
        // the 4 waves of a block take 4 consecutive tiles (same species).
        tileId = (bi & 7) * (P1TILES/8) + (bi >> 3) * 4 + wid;   // < 3072 <= total
        eBeg = 0; eEnd = NE;
    } else {
        int u = (bi - P1BLOCKS) * 4 + wid;
        tileId = P1TILES + (u >> 3);
        eBeg = u & 7; eEnd = eBeg + 1;
        if (tileId >= total) return;
    }

    int s = (tileId >= q3) ? 3 : (tileId >= q2) ? 2 : (tileId >= q1) ? 1 : 0;
    int tb = (s == 0) ? 0 : (s == 1) ? q1 : (s == 2) ? q2 : q3;
    int cs = (s == 0) ? c0 : (s == 1) ? c1 : (s == 2) ? c2 : c3;
    int rowBase = (tileId - tb) * TW;
    const int* myIdx = idx + s * BUCKET_CAP + rowBase;
    int nValid = cs - rowBase; if (nValid > TW) nValid = TW; if (nValid < 0) nValid = 0;

    int m = lane & 15, quad = lane >> 4;
    unsigned short (*X1)[S1STR] = (unsigned short (*)[S1STR])sBuf[wid];
    unsigned short (*X2)[S2STR] = (unsigned short (*)[S2STR])sBuf[wid];

    // ---- layer-1 AEV fragments (fp32->fp16), e-invariant ----
    h8v A1[2][12];
    #pragma unroll
    for (int mt = 0; mt < 2; mt++){
        int slot = mt*16 + m;
        int atom = myIdx[(slot < nValid) ? slot : 0];         // guarded pad
        if ((unsigned)atom >= N_ATOMS) atom = 0;              // clamp stale reads
        const float* ap = aev + (size_t)atom * D0 + quad*8;
        #pragma unroll
        for (int kt = 0; kt < 12; kt++){
            float4 u = *(const float4*)(ap + kt*32);
            float4 v = *(const float4*)(ap + kt*32 + 4);
            h8v f;
            f[0] = (_Float16)u.x; f[1] = (_Float16)u.y; f[2] = (_Float16)u.z; f[3] = (_Float16)u.w;
            f[4] = (_Float16)v.x; f[5] = (_Float16)v.y; f[6] = (_Float16)v.z; f[7] = (_Float16)v.w;
            A1[mt][kt] = f;
        }
    }

    // per-lane energy partials: e0 -> atom m, e1 -> atom 16+m (n-slices)
    float e0[4] = {0.f,0.f,0.f,0.f};
    float e1[4] = {0.f,0.f,0.f,0.f};

    #pragma unroll 1
    for (int e = eBeg; e < eEnd; e++){
        int net = s * NE + e;

        // ---------- layer 1: W1^T(frags) x A1 [K=384] -> X1[atom][n], N=160 ----------
        {
            const unsigned short* wf = W1b + (size_t)net * (D0*D1) + lane*8;
            f4v bc = *(const f4v*)(b1 + net*D1 + quad*4);     // bias n-slice, nt=0
            h8v Bb[2][12];
            #pragma unroll
            for (int kt = 0; kt < 12; kt++) Bb[0][kt] = *(const h8v*)(wf + kt*512);
            #pragma unroll
            for (int nt = 0; nt < 10; nt++){
                int cur = nt & 1, nxt = cur ^ 1;
                f4v bn = {0.f,0.f,0.f,0.f};
                if (nt < 9){
                    const unsigned short* bp = wf + (nt+1)*6144;
                    #pragma unroll
                    for (int kt = 0; kt < 12; kt++) Bb[nxt][kt] = *(const h8v*)(bp + kt*512);
                    bn = *(const f4v*)(b1 + net*D1 + (nt+1)*16 + quad*4);
                }
                f4v a0e = bc, a1e = bc;
                f4v a0o = {0.f,0.f,0.f,0.f}, a1o = a0o;
                #pragma unroll
                for (int kt = 0; kt < 12; kt += 2){
                    a0e = __builtin_amdgcn_mfma_f32_16x16x32_f16(Bb[cur][kt],   A1[0][kt],   a0e, 0, 0, 0);
                    a1e = __builtin_amdgcn_mfma_f32_16x16x32_f16(Bb[cur][kt],   A1[1][kt],   a1e, 0, 0, 0);
                    a0o = __builtin_amdgcn_mfma_f32_16x16x32_f16(Bb[cur][kt+1], A1[0][kt+1], a0o, 0, 0, 0);
                    a1o = __builtin_amdgcn_mfma_f32_16x16x32_f16(Bb[cur][kt+1], A1[1][kt+1], a1o, 0, 0, 0);
                }
                f4v a0 = a0e + a0o, a1 = a1e + a1o;
                h4v p0, p1;
                #pragma unroll
                for (int r = 0; r < 4; r++){
                    p0[r] = (_Float16)celu01(a0[r]);
                    p1[r] = (_Float16)celu01(a1[r]);
                }
                *(h4v*)&X1[m][nt*16 + quad*4]      = p0;      // 1 b64 per group
                *(h4v*)&X1[16 + m][nt*16 + quad*4] = p1;
                bc = bn;
            }
        }

        // ---------- layer 2: W2^T x X1 [K=160] -> X2[atom][n], N=128 ----------
        {
            h8v A2[2][5];                                     // X1 fragments (B-operand)
            #pragma unroll
            for (int mt = 0; mt < 2; mt++)
                #pragma unroll
                for (int kt = 0; kt < 5; kt++)
                    A2[mt][kt] = *(const h8v*)&X1[mt*16 + m][kt*32 + quad*8];
            const unsigned short* wf = W2b + (size_t)net * (D1*D2) + lane*8;
            f4v bc = *(const f4v*)(b2 + net*D2 + quad*4);
            h8v Bb[2][5];
            #pragma unroll
            for (int kt = 0; kt < 5; kt++) Bb[0][kt] = *(const h8v*)(wf + kt*512);
            #pragma unroll
            for (int nt = 0; nt < 8; nt++){
                int cur = nt & 1, nxt = cur ^ 1;
                f4v bn = {0.f,0.f,0.f,0.f};
                if (nt < 7){
                    const unsigned short* bp = wf + (nt+1)*2560;
                    #pragma unroll
                    for (int kt = 0; kt < 5; kt++) Bb[nxt][kt] = *(const h8v*)(bp + kt*512);
                    bn = *(const f4v*)(b2 + net*D2 + (nt+1)*16 + quad*4);
                }
                f4v a0e = bc, a1e = bc;
                f4v a0o = {0.f,0.f,0.f,0.f}, a1o = a0o;
                #pragma unroll
                for (int kt = 0; kt < 5; kt++){
                    if ((kt & 1) == 0){
                        a0e = __builtin_amdgcn_mfma_f32_16x16x32_f16(Bb[cur][kt], A2[0][kt], a0e, 0, 0, 0);
                        a1e = __builtin_amdgcn_mfma_f32_16x16x32_f16(Bb[cur][kt], A2[1][kt], a1e, 0, 0, 0);
                    } else {
                        a0o = __builtin_amdgcn_mfma_f32_16x16x32_f16(Bb[cur][kt], A2[0][kt], a0o, 0, 0, 0);
                        a1o = __builtin_amdgcn_mfma_f32_16x16x32_f16(Bb[cur][kt], A2[1][kt], a1o, 0, 0, 0);
                    }
                }
                f4v a0 = a0e + a0o, a1 = a1e + a1o;
                h4v p0, p1;
                #pragma unroll
                for (int r = 0; r < 4; r++){
                    p0[r] = (_Float16)celu01(a0[r]);
                    p1[r] = (_Float16)celu01(a1[r]);
                }
                *(h4v*)&X2[m][nt*16 + quad*4]      = p0;
                *(h4v*)&X2[16 + m][nt*16 + quad*4] = p1;
                bc = bn;
            }
        }

        // ---------- layer 3 + 4 fused: W3^T x X2 [K=128] -> per-lane energies ----------
        {
            h8v A3[2][4];
            #pragma unroll
            for (int mt = 0; mt < 2; mt++)
                #pragma unroll
                for (int kt = 0; kt < 4; kt++)
                    A3[mt][kt] = *(const h8v*)&X2[mt*16 + m][kt*32 + quad*8];
            const unsigned short* wf = W3b + (size_t)net * (D2*D3) + lane*8;
            const float* w4 = W4 + net * D3;
            f4v bc = *(const f4v*)(b3 + net*D3 + quad*4);
            f4v wc = *(const f4v*)(w4 + quad*4);
            h8v Bb[2][4];
            #pragma unroll
            for (int kt = 0; kt < 4; kt++) Bb[0][kt] = *(const h8v*)(wf + kt*512);
            #pragma unroll
            for (int nt = 0; nt < 6; nt++){
                int cur = nt & 1, nxt = cur ^ 1;
                f4v bn = {0.f,0.f,0.f,0.f}, wn = bn;
                if (nt < 5){
                    const unsigned short* bp = wf + (nt+1)*2048;
                    #pragma unroll
                    for (int kt = 0; kt < 4; kt++) Bb[nxt][kt] = *(const h8v*)(bp + kt*512);
                    bn = *(const f4v*)(b3 + net*D3 + (nt+1)*16 + quad*4);
                    wn = *(const f4v*)(w4 + (nt+1)*16 + quad*4);
                }
                f4v a0e = bc, a1e = bc;
                f4v a0o = {0.f,0.f,0.f,0.f}, a1o = a0o;
                #pragma unroll
                for (int kt = 0; kt < 4; kt += 2){
                    a0e = __builtin_amdgcn_mfma_f32_16x16x32_f16(Bb[cur][kt],   A3[0][kt],   a0e, 0, 0, 0);
                    a1e = __builtin_amdgcn_mfma_f32_16x16x32_f16(Bb[cur][kt],   A3[1][kt],   a1e, 0, 0, 0);
                    a0o = __builtin_amdgcn_mfma_f32_16x16x32_f16(Bb[cur][kt+1], A3[0][kt+1], a0o, 0, 0, 0);
                    a1o = __builtin_amdgcn_mfma_f32_16x16x32_f16(Bb[cur][kt+1], A3[1][kt+1], a1o, 0, 0, 0);
                }
                f4v a0 = a0e + a0o, a1 = a1e + a1o;
                #pragma unroll
                for (int r = 0; r < 4; r++){
                    e0[r] = fmaf(celu01(a0[r]), wc[r], e0[r]);
                    e1[r] = fmaf(celu01(a1[r]), wc[r], e1[r]);
                }
                bc = bn; wc = wn;
            }
        }
    }

    // ---- final: quad-reduce n-slices per atom, mask, 4-shuffle sum, one atomic ----
    {
        float er0 = e0[0] + e0[1] + e0[2] + e0[3];            // atom m, this quad's n
        float er1 = e1[0] + e1[1] + e1[2] + e1[3];            // atom 16+m
        er0 += __shfl_xor(er0, 16, 64);                       // sum over 4 quads
        er0 += __shfl_xor(er0, 32, 64);
        er1 += __shfl_xor(er1, 16, 64);
        er1 += __shfl_xor(er1, 32, 64);
        float tot = (quad == 0) ? (((m      < nValid) ? er0 : 0.f) +
                                   ((16 + m < nValid) ? er1 : 0.f)) : 0.f;
        tot += __shfl_xor(tot, 1, 64);
        tot += __shfl_xor(tot, 2, 64);
        tot += __shfl_xor(tot, 4, 64);
        tot += __shfl_xor(tot, 8, 64);
        if (lane == 0 && nValid > 0){
            float sb4 = 0.f;
            for (int e = eBeg; e < eEnd; e++) sb4 += b4[s*NE + e];
            atomicAdd(out, (tot + (float)nValid * sb4) * 0.125f);
        }
    }
}

extern "C" void kernel_launch(void* const* d_in, const int* in_sizes, int n_in,
                              void* d_out, int out_size, void* d_ws, size_t ws_size,
                              hipStream_t stream){
    const float* aev     = (const float*)d_in[0];
    const int*   species = (const int*)  d_in[1];
    const float* W1 = (const float*)d_in[2];
    const float* b1 = (const float*)d_in[3];
    const float* W2 = (const float*)d_in[4];
    const float* b2 = (const float*)d_in[5];
    const float* W3 = (const float*)d_in[6];
    const float* b3 = (const float*)d_in[7];
    const float* W4 = (const float*)d_in[8];
    const float* b4 = (const float*)d_in[9];
    float* out = (float*)d_out;

    int* hdr = (int*)d_ws;
    int* idx = (int*)((char*)d_ws + IDX_OFF_B);
    unsigned short* W1b = (unsigned short*)((char*)d_ws + W1B_OFF);
    unsigned short* W2b = (unsigned short*)((char*)d_ws + W2B_OFF);
    unsigned short* W3b = (unsigned short*)((char*)d_ws + W3B_OFF);

    k_init   <<<1, 64, 0, stream>>>(hdr, out);
    k_scatter<<<(N_ATOMS + 255)/256, 256, 0, stream>>>(species, hdr, idx);
    int convTot = W1_TOT + W2_TOT + W3_TOT;
    k_convert<<<(convTot + 255)/256, 256, 0, stream>>>(W1, W2, W3, W1b, W2b, W3b);
    k_mlp    <<<GRID_MLP, 256, 0, stream>>>(aev, hdr, idx, W1b, W2b, W3b,
                                            b1, b2, b3, W4, b4, out);
}